// Round 10
// baseline (2490.856 us; speedup 1.0000x reference)
//
#include <hip/hip_runtime.h>

// ReservoirLayer: S0 = pad(x,[2048,4096]); 16x: S = leaky_relu(S @ W, 0.1)
// fp32-emulation via fp16 hi/lo split (fp16x3): acc = Sh@Wh + Sl@Wh + Sh@Wl.
// R13: OCCUPANCY attack. Evidence: R3/R6/R8/R10/R12 all pinned at 175-185us,
//     MfmaUtil 51-54%, Occupancy ~20%, regardless of MFMA shape, LDS layout,
//     conflicts, LDS volume, or sync style -> latency/occupancy-bound at
//     2 waves/SIMD (grid 512 x 256thr = 2 blocks/CU). This round: 512-thread
//     blocks (8 waves, 2x4 grid, 64x32/wave), same 128x128 tile, same grid
//     512 -> 16 waves/CU = 4 waves/SIMD. Single fragment set (TLP replaces
//     ILP) keeps VGPR <= 128 (__launch_bounds__(512,4)). R3's proven LDS
//     layout + staging (0 conflicts) and R10's counted-vmcnt raw barriers.

#define BATCH 2048
#define NDIM  4096
#define INDIM 512
#define BM 128
#define BN 128
#define BK 32

typedef _Float16 f16x8 __attribute__((ext_vector_type(8)));
typedef float    f32x4 __attribute__((ext_vector_type(4)));

__device__ __forceinline__ void async16(const void* gsrc, void* ldst) {
  const __attribute__((address_space(1))) unsigned int* g =
      (const __attribute__((address_space(1))) unsigned int*)gsrc;
  __attribute__((address_space(3))) unsigned int* l =
      (__attribute__((address_space(3))) unsigned int*)ldst;
  __builtin_amdgcn_global_load_lds(g, l, 16, 0, 0);
}

#define WAITV4() do { asm volatile("s_waitcnt vmcnt(4)" ::: "memory"); \
                      __builtin_amdgcn_sched_barrier(0); } while (0)
#define WAITV0() do { asm volatile("s_waitcnt vmcnt(0)" ::: "memory"); \
                      __builtin_amdgcn_sched_barrier(0); } while (0)
#define LGKM0()  do { asm volatile("s_waitcnt lgkmcnt(0)" ::: "memory"); \
                      __builtin_amdgcn_sched_barrier(0); } while (0)
#define SBAR()   __builtin_amdgcn_s_barrier()

// ---------------- prep: split+pad x into S_hi/S_lo ----------------
__global__ void prep_x(const float* __restrict__ x,
                       _Float16* __restrict__ Sh, _Float16* __restrict__ Sl) {
  size_t i = (size_t)blockIdx.x * 256 + threadIdx.x;  // over BATCH*NDIM
  int b = (int)(i >> 12);
  int n = (int)(i & (NDIM - 1));
  float v = (n < INDIM) ? x[(size_t)b * INDIM + n] : 0.0f;
  _Float16 h = (_Float16)v;
  Sh[i] = h;
  Sl[i] = (_Float16)(v - (float)h);
}

// ---------------- prep: transpose + scale(256) + split W ----------------
__global__ void prep_w(const float* __restrict__ W,
                       _Float16* __restrict__ Wth, _Float16* __restrict__ Wtl) {
  __shared__ float tile[32][33];
  int k0 = blockIdx.y * 32, n0 = blockIdx.x * 32;
  int tx = threadIdx.x, ty = threadIdx.y;  // 32 x 8
  for (int r = 0; r < 4; r++) {
    int k = k0 + ty + r * 8;
    tile[ty + r * 8][tx] = W[(size_t)k * NDIM + n0 + tx];
  }
  __syncthreads();
  for (int r = 0; r < 4; r++) {
    int n = n0 + ty + r * 8;
    float v = tile[tx][ty + r * 8] * 256.0f;
    _Float16 h = (_Float16)v;
    Wth[(size_t)n * NDIM + k0 + tx] = h;
    Wtl[(size_t)n * NDIM + k0 + tx] = (_Float16)(v - (float)h);
  }
}

// single frag set: A(4 row-frags) + B(2 col-frags), hi/lo each
#define READF(b)                                       \
  do {                                                 \
    _Pragma("unroll") for (int i = 0; i < 4; i++) {    \
      af[i] = *(const f16x8*)&sAh[b][oA[i]];           \
      lf[i] = *(const f16x8*)&sAl[b][oA[i]];           \
    }                                                  \
    _Pragma("unroll") for (int j = 0; j < 2; j++) {    \
      bf[j] = *(const f16x8*)&sBh[b][oB[j]];           \
      mf[j] = *(const f16x8*)&sBl[b][oB[j]];           \
    }                                                  \
  } while (0)

// term-major: same-acc reuse distance 8; per-acc order AB -> LB -> AM
#define MFMAS()                                                                     \
  do {                                                                              \
    _Pragma("unroll") for (int j = 0; j < 2; j++)                                   \
    _Pragma("unroll") for (int i = 0; i < 4; i++)                                   \
      acc[i][j] = __builtin_amdgcn_mfma_f32_16x16x32_f16(af[i], bf[j], acc[i][j], 0, 0, 0); \
    _Pragma("unroll") for (int j = 0; j < 2; j++)                                   \
    _Pragma("unroll") for (int i = 0; i < 4; i++)                                   \
      acc[i][j] = __builtin_amdgcn_mfma_f32_16x16x32_f16(lf[i], bf[j], acc[i][j], 0, 0, 0); \
    _Pragma("unroll") for (int j = 0; j < 2; j++)                                   \
    _Pragma("unroll") for (int i = 0; i < 4; i++)                                   \
      acc[i][j] = __builtin_amdgcn_mfma_f32_16x16x32_f16(af[i], mf[j], acc[i][j], 0, 0, 0); \
  } while (0)

// ---------------- one recurrence step ----------------
template <int MODE>
__global__ __launch_bounds__(512, 4) void step_kernel(
    const _Float16* __restrict__ Ah, const _Float16* __restrict__ Al,
    const _Float16* __restrict__ Bh, const _Float16* __restrict__ Bl,
    _Float16* __restrict__ Dh, _Float16* __restrict__ Dl,
    float* __restrict__ Dout, int k_len) {
  __shared__ _Float16 sAh[2][BM * BK];
  __shared__ _Float16 sAl[2][BM * BK];
  __shared__ _Float16 sBh[2][BN * BK];
  __shared__ _Float16 sBl[2][BN * BK];

  const int tid = threadIdx.x;       // 0..511
  const int lane = tid & 63;
  const int w = tid >> 6;            // 0..7
  const int wm = w >> 2, wn = w & 3; // 2 x 4 wave grid, 64x32 per wave

  // XCD-aware swizzle: 8x8 block region per XCD (round-robin dispatch, id&7)
  int id = blockIdx.x;
  int xcd = id & 7, local = id >> 3;
  int lr = local & 7, lc = local >> 3;
  const int bm = ((xcd & 1) * 8 + lr) * BM;
  const int bn = ((xcd >> 1) * 8 + lc) * BN;

  const int sr = lane >> 2, cl = lane & 3;
  const int fm = lane & 15, fq = lane >> 4;

  // loop-invariant LDS fragment element-offsets (R3's k-chunk XOR pattern)
  int oA[4], oB[2];
#pragma unroll
  for (int i = 0; i < 4; i++) {
    int rA = wm * 64 + i * 16 + fm;
    oA[i] = rA * BK + (fq ^ ((rA >> 1) & 3)) * 8;
  }
#pragma unroll
  for (int j = 0; j < 2; j++) {
    int rB = wn * 32 + j * 16 + fm;
    oB[j] = rB * BK + (fq ^ ((rB >> 1) & 3)) * 8;
  }

  // staging: wave w stages rows [w*16, w*16+16) of all 4 arrays.
  // 4 lanes/row, 64B contiguous per row; LDS dst lane-linear (= w*512+lane*8).
  int r0 = w * 16 + sr;
  int cg0 = cl ^ ((r0 >> 1) & 3);
  const size_t gA0 = (size_t)(bm + r0) * NDIM + cg0 * 8;
  const size_t gB0 = (size_t)(bn + r0) * NDIM + cg0 * 8;
  const int lo0 = r0 * BK + cl * 8;

  auto stage = [&](int kt, int b) {   // 4 global_load_lds per wave
    async16(Ah + gA0 + kt, &sAh[b][lo0]);
    async16(Al + gA0 + kt, &sAl[b][lo0]);
    async16(Bh + gB0 + kt, &sBh[b][lo0]);
    async16(Bl + gB0 + kt, &sBl[b][lo0]);
  };

  f32x4 acc[4][2];
#pragma unroll
  for (int i = 0; i < 4; i++)
#pragma unroll
    for (int j = 0; j < 2; j++) acc[i][j] = (f32x4){0.f, 0.f, 0.f, 0.f};

  f16x8 af[4], lf[4], bf[2], mf[2];

  const int nk = k_len / BK;  // 16 or 128

  // depth-2 staging pipeline, single frag set, counted vmcnt
  stage(0 * BK, 0);
  stage(1 * BK, 1);
  for (int it = 0; it < nk; ++it) {
    const int p = it & 1;
    if (it + 1 < nk) { WAITV4(); } else { WAITV0(); }  // stage(it) landed
    SBAR();
    READF(p);                       // 12 ds_read_b128
    LGKM0(); SBAR();                // all waves' reads of buf p retired
    if (it + 2 < nk) stage((it + 2) * BK, p);
    MFMAS();                        // 24 MFMAs cover stage latency
  }

  // ---- epilogue: undo 256x W-scale, leaky relu, write next state / output
  const float inv = 1.0f / 256.0f;
#pragma unroll
  for (int i = 0; i < 4; i++) {
#pragma unroll
    for (int j = 0; j < 2; j++) {
#pragma unroll
      for (int e = 0; e < 4; e++) {
        int r = bm + wm * 64 + i * 16 + fq * 4 + e;  // C/D: row=(lane>>4)*4+reg
        int c = bn + wn * 32 + j * 16 + fm;          //      col=lane&15
        float g = acc[i][j][e] * inv;
        float s = (g > 0.0f) ? g : 0.1f * g;
        if (MODE == 0) {
          _Float16 h = (_Float16)s;
          Dh[(size_t)r * NDIM + c] = h;
          Dl[(size_t)r * NDIM + c] = (_Float16)(s - (float)h);
        } else {
          Dout[(size_t)r * NDIM + c] = s;
        }
      }
    }
  }
}

extern "C" void kernel_launch(void* const* d_in, const int* in_sizes, int n_in,
                              void* d_out, int out_size, void* d_ws, size_t ws_size,
                              hipStream_t stream) {
  const float* x = (const float*)d_in[0];  // [2048, 512]
  const float* W = (const float*)d_in[1];  // [4096, 4096]
  float* out = (float*)d_out;              // [2048, 4096]
  char* ws = (char*)d_ws;

  const size_t WT_BYTES = (size_t)NDIM * NDIM * 2;  // 32 MB each
  const size_t S_BYTES = (size_t)BATCH * NDIM * 2;  // 16 MB each
  _Float16* Wth = (_Float16*)ws;
  _Float16* Wtl = (_Float16*)(ws + WT_BYTES);
  _Float16* SAh = (_Float16*)(ws + 2 * WT_BYTES);
  _Float16* SAl = (_Float16*)(ws + 2 * WT_BYTES + S_BYTES);
  _Float16* SBh = (_Float16*)(ws + 2 * WT_BYTES + 2 * S_BYTES);
  _Float16* SBl = (_Float16*)(ws + 2 * WT_BYTES + 3 * S_BYTES);

  prep_x<<<(BATCH * NDIM) / 256, 256, 0, stream>>>(x, SAh, SAl);
  prep_w<<<dim3(NDIM / 32, NDIM / 32), dim3(32, 8), 0, stream>>>(W, Wth, Wtl);

  dim3 grid((NDIM / BN) * (BATCH / BM));  // 512 blocks x 512 threads
  for (int t = 1; t <= 16; t++) {
    const _Float16* ah = (t & 1) ? SAh : SBh;
    const _Float16* al = (t & 1) ? SAl : SBl;
    _Float16* dh = (t & 1) ? SBh : SAh;
    _Float16* dl = (t & 1) ? SBl : SAl;
    int klen = (t == 1) ? INDIM : NDIM;
    if (t < 16)
      step_kernel<0><<<grid, 512, 0, stream>>>(ah, al, Wth, Wtl, dh, dl, nullptr, klen);
    else
      step_kernel<1><<<grid, 512, 0, stream>>>(ah, al, Wth, Wtl, nullptr, nullptr, out, klen);
  }
}